// Round 1
// baseline (132.188 us; speedup 1.0000x reference)
//
#include <hip/hip_runtime.h>

// Bidirectional NN-MSE loss:
//   loss = w * mean_n min_j ||p_n - g_j||^2 / 3  ... (mean over N*3 elems)
//        + (1-w) * mean_m min_i ||g_m - p_i||^2 / 3
// Insight: the gathered (pred - align_gt)^2 summed over xyz IS the min
// squared distance, so no argmin/gather is needed — only min distance.

#define BLOCK   256
#define QPT     4                      // queries per thread (register tile)
#define CHUNK   512                    // refs staged in LDS per block
#define NPTS    16384
#define QCHUNKS (NPTS / (BLOCK * QPT)) // 16
#define RCHUNKS (NPTS / CHUNK)         // 32

// Order-preserving float->uint key (works for negative values too, needed
// because we defer adding qq so tracked values can be negative).
__device__ __forceinline__ unsigned f2key(float f) {
    unsigned b = __float_as_uint(f);
    return (b & 0x80000000u) ? ~b : (b | 0x80000000u);
}
__device__ __forceinline__ float key2f(unsigned k) {
    unsigned b = (k & 0x80000000u) ? (k & 0x7FFFFFFFu) : ~k;
    return __uint_as_float(b);
}

__global__ __launch_bounds__(BLOCK) void nn_min_kernel(
    const float* __restrict__ pred, const float* __restrict__ gt,
    unsigned* __restrict__ keys)
{
    const int dir = blockIdx.z;            // 0: Q=pred vs R=gt ; 1: Q=gt vs R=pred
    const float* __restrict__ Q = dir ? gt : pred;
    const float* __restrict__ R = dir ? pred : gt;
    unsigned* kout = keys + dir * NPTS;

    __shared__ float4 lref[CHUNK];
    const int t = threadIdx.x;
    const int rbase = blockIdx.y * CHUNK;

    // Stage ref chunk into LDS with precomputed ||r||^2.
    for (int i = t; i < CHUNK; i += BLOCK) {
        float x = R[(rbase + i) * 3 + 0];
        float y = R[(rbase + i) * 3 + 1];
        float z = R[(rbase + i) * 3 + 2];
        lref[i] = make_float4(x, y, z, x * x + y * y + z * z);
    }

    // Register-resident queries (4 per thread, strided for coalescing).
    const int qbase = blockIdx.x * (BLOCK * QPT);
    float qx[QPT], qy[QPT], qz[QPT], mn[QPT];
    int qi[QPT];
#pragma unroll
    for (int u = 0; u < QPT; ++u) {
        qi[u] = qbase + u * BLOCK + t;
        qx[u] = Q[qi[u] * 3 + 0];
        qy[u] = Q[qi[u] * 3 + 1];
        qz[u] = Q[qi[u] * 3 + 2];
        mn[u] = 3.4e38f;
    }
    __syncthreads();

    // Main loop: track min of (rr - 2*q.r); qq added once at the end.
#pragma unroll 4
    for (int k = 0; k < CHUNK; ++k) {
        float4 r = lref[k];  // wave-uniform address -> LDS broadcast
#pragma unroll
        for (int u = 0; u < QPT; ++u) {
            float dot = qx[u] * r.x + qy[u] * r.y + qz[u] * r.z;
            float d2  = fmaf(-2.0f, dot, r.w);
            mn[u] = fminf(mn[u], d2);
        }
    }

#pragma unroll
    for (int u = 0; u < QPT; ++u) {
        float qq = qx[u] * qx[u] + qy[u] * qy[u] + qz[u] * qz[u];
        atomicMin(&kout[qi[u]], f2key(mn[u] + qq));
    }
}

__global__ __launch_bounds__(1024) void reduce_kernel(
    const unsigned* __restrict__ keys, const float* __restrict__ weight,
    float* __restrict__ out)
{
    const int t = threadIdx.x;
    float s0 = 0.f, s1 = 0.f;
    for (int i = t; i < NPTS; i += 1024) {
        s0 += key2f(keys[i]);
        s1 += key2f(keys[NPTS + i]);
    }
    // wave (64-lane) reduction
    for (int off = 32; off; off >>= 1) {
        s0 += __shfl_down(s0, off, 64);
        s1 += __shfl_down(s1, off, 64);
    }
    __shared__ float ws0[16], ws1[16];
    const int w = t >> 6;
    if ((t & 63) == 0) { ws0[w] = s0; ws1[w] = s1; }
    __syncthreads();
    if (t == 0) {
        float a = 0.f, b = 0.f;
        for (int i = 0; i < 16; ++i) { a += ws0[i]; b += ws1[i]; }
        const float wgt = weight[0];
        const float inv = 1.0f / (3.0f * (float)NPTS);
        out[0] = wgt * (a * inv) + (1.0f - wgt) * (b * inv);
    }
}

extern "C" void kernel_launch(void* const* d_in, const int* in_sizes, int n_in,
                              void* d_out, int out_size, void* d_ws, size_t ws_size,
                              hipStream_t stream) {
    const float* pred   = (const float*)d_in[0];
    const float* gt     = (const float*)d_in[1];
    const float* weight = (const float*)d_in[2];
    unsigned* keys = (unsigned*)d_ws;   // 2 * NPTS uint keys

    // init keys to 0xFFFFFFFF (max uint -> +inf in key space)
    hipMemsetAsync(keys, 0xFF, 2 * NPTS * sizeof(unsigned), stream);

    dim3 grid(QCHUNKS, RCHUNKS, 2);
    nn_min_kernel<<<grid, BLOCK, 0, stream>>>(pred, gt, keys);
    reduce_kernel<<<1, 1024, 0, stream>>>(keys, weight, (float*)d_out);
}

// Round 2
// 107.932 us; speedup vs baseline: 1.2247x; 1.2247x over previous
//
#include <hip/hip_runtime.h>

// Bidirectional NN-MSE via MFMA.
//   loss = w * mean_n min_j ||p_n - g_j||^2 + (1-w) * mean_m min_i ||g_m - p_i||^2
// d^2 = qq - 2 q.r + rr is computed INSIDE mfma_f32_32x32x16_bf16 (K=16):
//   per coord c: 4 slots (ch_q*ch_r, ch_q*cl_r, cl_q*ch_r, cl_q*cl_r) with the
//   A side pre-scaled by -2  -> exact -2*q.r to 2-term bf16 split precision
//   slots 12,13: (1, rr_h/l) ; slots 14,15: (qq_h/l, 1)
// bf16 x bf16 products are exact in fp32 (8x8 mantissa bits), so the only
// error is the 2-term split truncation ~ |q||r| * 2^-17 ~ 1e-5 per d^2.

#define NPTS   16384
#define QT     4        // query tiles (32 queries each) per wave
#define SSPLIT 16       // ref-range splits (parallelism); 32 ref tiles each

typedef __attribute__((ext_vector_type(8)))  __bf16 bf16x8;
typedef __attribute__((ext_vector_type(16))) float  floatx16;

__device__ __forceinline__ unsigned f2key(float f) {
    unsigned b = __float_as_uint(f);
    return (b & 0x80000000u) ? ~b : (b | 0x80000000u);
}
__device__ __forceinline__ float key2f(unsigned k) {
    unsigned b = (k & 0x80000000u) ? (k & 0x7FFFFFFFu) : ~k;
    return __uint_as_float(b);
}

// One thread per point-role: builds the 16-slot A-form (query) and B-form
// (ref) bf16 fragment arrays, and initializes the min-keys (folds the memset).
__global__ __launch_bounds__(256) void prep_kernel(
    const float* __restrict__ pred, const float* __restrict__ gt,
    unsigned* __restrict__ keys, unsigned short* __restrict__ frag)
{
    const int i = blockIdx.x * 256 + threadIdx.x;   // 0 .. 2*NPTS-1
    keys[i] = 0xFFFFFFFFu;
    const bool isPred = (i < NPTS);
    const int p = isPred ? i : i - NPTS;
    const float* __restrict__ src = isPred ? pred : gt;
    const float x = src[p * 3 + 0], y = src[p * 3 + 1], z = src[p * 3 + 2];
    const float nn = x * x + y * y + z * z;

    const __bf16 xh = (__bf16)x, yh = (__bf16)y, zh = (__bf16)z;
    const __bf16 xl = (__bf16)(x - (float)xh);
    const __bf16 yl = (__bf16)(y - (float)yh);
    const __bf16 zl = (__bf16)(z - (float)zh);
    const __bf16 nh = (__bf16)nn;
    const __bf16 nl = (__bf16)(nn - (float)nh);
    const __bf16 one = (__bf16)1.0f;
    const __bf16 m2xh = (__bf16)(-2.0f * (float)xh), m2xl = (__bf16)(-2.0f * (float)xl);
    const __bf16 m2yh = (__bf16)(-2.0f * (float)yh), m2yl = (__bf16)(-2.0f * (float)yl);
    const __bf16 m2zh = (__bf16)(-2.0f * (float)zh), m2zl = (__bf16)(-2.0f * (float)zl);

    union { __bf16 v[16]; uint4 q[2]; } A, B;
    A.v[0] = m2xh; A.v[1] = m2xh; A.v[2]  = m2xl; A.v[3]  = m2xl;
    A.v[4] = m2yh; A.v[5] = m2yh; A.v[6]  = m2yl; A.v[7]  = m2yl;
    A.v[8] = m2zh; A.v[9] = m2zh; A.v[10] = m2zl; A.v[11] = m2zl;
    A.v[12] = one; A.v[13] = one; A.v[14] = nh;   A.v[15] = nl;

    B.v[0] = xh; B.v[1] = xl; B.v[2]  = xh; B.v[3]  = xl;
    B.v[4] = yh; B.v[5] = yl; B.v[6]  = yh; B.v[7]  = yl;
    B.v[8] = zh; B.v[9] = zl; B.v[10] = zh; B.v[11] = zl;
    B.v[12] = nh; B.v[13] = nl; B.v[14] = one; B.v[15] = one;

    // roles: 0=A_pred 1=B_pred 2=A_gt 3=B_gt ; 32 B per point, uint4-aligned
    uint4* dA = (uint4*)(frag + ((size_t)((isPred ? 0 : 2) * NPTS + p)) * 16);
    uint4* dB = (uint4*)(frag + ((size_t)((isPred ? 1 : 3) * NPTS + p)) * 16);
    dA[0] = A.q[0]; dA[1] = A.q[1];
    dB[0] = B.q[0]; dB[1] = B.q[1];
}

// Fragment layouts (32x32x16 bf16):
//   A[m][k]: m = lane&31, k = (lane>>5)*8 + j  (8 contiguous slots / lane)
//   B[k][n]: n = lane&31, k = (lane>>5)*8 + j
//   C/D    : col(n) = lane&31, row(m) = (reg&3) + 8*(reg>>2) + 4*(lane>>5)
__global__ __launch_bounds__(256) void nn_mfma_kernel(
    const unsigned short* __restrict__ frag, unsigned* __restrict__ keys)
{
    const int qg   = blockIdx.x;        // 0..63 : 32 query-blocks x 2 dirs
    const int s    = blockIdx.y;        // 0..SSPLIT-1 : ref range
    const int dir  = qg >> 5;           // 0: Q=pred,R=gt ; 1: Q=gt,R=pred
    const int lane = threadIdx.x & 63;
    const int wave = threadIdx.x >> 6;
    const int lid  = lane & 31;
    const int half = lane >> 5;

    const uint4* __restrict__ A = (const uint4*)(frag + (size_t)(dir ? 2 : 0) * NPTS * 16);
    const uint4* __restrict__ B = (const uint4*)(frag + (size_t)(dir ? 1 : 3) * NPTS * 16);

    const int qbase = (qg & 31) * 512 + wave * 128;   // first query of this wave

    bf16x8 af[QT];
#pragma unroll
    for (int qt = 0; qt < QT; ++qt) {
        const int pt = qbase + qt * 32 + lid;
        af[qt] = __builtin_bit_cast(bf16x8, A[pt * 2 + half]);
    }

    floatx16 zero;
#pragma unroll
    for (int k = 0; k < 16; ++k) zero[k] = 0.0f;
    floatx16 mn[QT];
#pragma unroll
    for (int qt = 0; qt < QT; ++qt)
#pragma unroll
        for (int k = 0; k < 16; ++k) mn[qt][k] = 3.4e38f;

    // iterate 32 ref tiles (2 per iteration), prefetching next pair
    const uint4* bp = B + (size_t)(s * 1024 + lid) * 2 + half;
    uint4 nb0 = bp[0];
    uint4 nb1 = bp[64];
    for (int it = 0; it < 16; ++it) {
        const uint4 c0 = nb0, c1 = nb1;
        if (it < 15) { bp += 128; nb0 = bp[0]; nb1 = bp[64]; }
        const bf16x8 b0 = __builtin_bit_cast(bf16x8, c0);
        const bf16x8 b1 = __builtin_bit_cast(bf16x8, c1);
#pragma unroll
        for (int qt = 0; qt < QT; ++qt) {
            floatx16 a0 = __builtin_amdgcn_mfma_f32_32x32x16_bf16(af[qt], b0, zero, 0, 0, 0);
            floatx16 a1 = __builtin_amdgcn_mfma_f32_32x32x16_bf16(af[qt], b1, zero, 0, 0, 0);
#pragma unroll
            for (int k = 0; k < 16; ++k)          // -> v_min3_f32
                mn[qt][k] = fminf(fminf(mn[qt][k], a0[k]), a1[k]);
        }
    }

    // reduce over the 32 ref-columns (lanes within each 32-half), then one
    // atomicMin per query row (2 active lanes per k: lid==k in each half).
    unsigned* kout = keys + dir * NPTS;
#pragma unroll
    for (int qt = 0; qt < QT; ++qt) {
#pragma unroll
        for (int k = 0; k < 16; ++k) {
            float v = mn[qt][k];
            v = fminf(v, __shfl_xor(v, 16));
            v = fminf(v, __shfl_xor(v, 8));
            v = fminf(v, __shfl_xor(v, 4));
            v = fminf(v, __shfl_xor(v, 2));
            v = fminf(v, __shfl_xor(v, 1));
            if (lid == k) {
                const int row = (k & 3) + ((k >> 2) << 3) + (half << 2);
                atomicMin(&kout[qbase + qt * 32 + row], f2key(v));
            }
        }
    }
}

__global__ __launch_bounds__(1024) void reduce_kernel(
    const unsigned* __restrict__ keys, const float* __restrict__ weight,
    float* __restrict__ out)
{
    const int t = threadIdx.x;
    const uint4* k4 = (const uint4*)keys;   // 8192 uint4 (dir0: 0..4095)
    float s0 = 0.f, s1 = 0.f;
#pragma unroll
    for (int i = 0; i < 8; ++i) {
        const uint4 v = k4[i * 1024 + t];
        const float f = key2f(v.x) + key2f(v.y) + key2f(v.z) + key2f(v.w);
        if (i < 4) s0 += f; else s1 += f;
    }
    for (int off = 32; off; off >>= 1) {
        s0 += __shfl_down(s0, off);
        s1 += __shfl_down(s1, off);
    }
    __shared__ float ws0[16], ws1[16];
    const int w = t >> 6;
    if ((t & 63) == 0) { ws0[w] = s0; ws1[w] = s1; }
    __syncthreads();
    if (t == 0) {
        float a = 0.f, b = 0.f;
        for (int i = 0; i < 16; ++i) { a += ws0[i]; b += ws1[i]; }
        const float wgt = weight[0];
        const float inv = 1.0f / (3.0f * (float)NPTS);
        out[0] = wgt * (a * inv) + (1.0f - wgt) * (b * inv);
    }
}

extern "C" void kernel_launch(void* const* d_in, const int* in_sizes, int n_in,
                              void* d_out, int out_size, void* d_ws, size_t ws_size,
                              hipStream_t stream) {
    const float* pred   = (const float*)d_in[0];
    const float* gt     = (const float*)d_in[1];
    const float* weight = (const float*)d_in[2];

    // ws layout: [keys: 2*NPTS u32 = 128 KB][frag: 4*NPTS*16 bf16 = 2 MB]
    unsigned* keys = (unsigned*)d_ws;
    unsigned short* frag = (unsigned short*)((char*)d_ws + (size_t)2 * NPTS * sizeof(unsigned));

    prep_kernel<<<2 * NPTS / 256, 256, 0, stream>>>(pred, gt, keys, frag);
    nn_mfma_kernel<<<dim3(64, SSPLIT), 256, 0, stream>>>(frag, keys);
    reduce_kernel<<<1, 1024, 0, stream>>>(keys, weight, (float*)d_out);
}